// Round 9
// baseline (353.570 us; speedup 1.0000x reference)
//
#include <hip/hip_runtime.h>

#define NB 8
#define NN 2048
#define DF 128
#define NF 128

typedef __attribute__((ext_vector_type(8))) __bf16 bf16x8;
typedef __attribute__((ext_vector_type(4))) float f32x4;
typedef __attribute__((ext_vector_type(8))) unsigned short u16x8;
typedef __attribute__((ext_vector_type(4))) unsigned short u16x4;

__device__ inline unsigned short f2bf(float f) {
    unsigned int u = __float_as_uint(f);
    u += 0x7FFFu + ((u >> 16) & 1u);   // round-to-nearest-even
    return (unsigned short)(u >> 16);
}

// K1: one streaming pass over A, BATCH-STRUCTURED for MLP:
//   per batch: 4 independent loads FIRST (static-indexed regs), then 4 fp32
//   stores, then converts + bf16 stores. Forces 4 loads in flight per wave.
// Grid 8b x 8jt x 32it = 2048 blocks (64row x 256col tiles) -> 8 blocks/CU,
// 32 waves/CU for store-ack stagger. outA copy + Ab16=bf16(A+I) + colsum.
__global__ __launch_bounds__(256) void k_stream(const float* __restrict__ A,
                                                float* __restrict__ outA,
                                                unsigned short* __restrict__ Ab16,
                                                float* __restrict__ colsum) {
    int bid = blockIdx.x;
    int it = bid & 31;            // 32 row-tiles of 64 rows
    int jt = (bid >> 5) & 7;      // 8 col-tiles of 256 cols
    int b  = bid >> 8;
    int t  = threadIdx.x;
    int jq = t & 63;              // float4 column within 256-col tile
    int ir = t >> 6;              // 0..3 row phase
    const float*    Ap = A    + (size_t)b * NN * NN;
    float*          Op = outA + (size_t)b * NN * NN;
    unsigned short* Bp = Ab16 + (size_t)b * NN * NN;   // u16 units, row-major
    int j  = jt * 256 + jq * 4;
    int r0 = it * 64;
    float4 s = make_float4(0.f, 0.f, 0.f, 0.f);

    for (int p = 0; p < 4; p++) {
        int rbase = r0 + p * 16 + ir;
        float4 v[4];
#pragma unroll
        for (int k = 0; k < 4; k++)              // 4 loads issued back-to-back
            v[k] = *(const float4*)(Ap + (size_t)(rbase + k * 4) * NN + j);
#pragma unroll
        for (int k = 0; k < 4; k++)              // fp32 copy stores
            *(float4*)(Op + (size_t)(rbase + k * 4) * NN + j) = v[k];
#pragma unroll
        for (int k = 0; k < 4; k++) {            // converts + bf16 stores
            int i = rbase + k * 4;
            s.x += v[k].x; s.y += v[k].y; s.z += v[k].z; s.w += v[k].w;
            u16x4 u;
            u[0] = f2bf(v[k].x + ((i == j + 0) ? 1.0f : 0.0f));   // +I fused
            u[1] = f2bf(v[k].y + ((i == j + 1) ? 1.0f : 0.0f));
            u[2] = f2bf(v[k].z + ((i == j + 2) ? 1.0f : 0.0f));
            u[3] = f2bf(v[k].w + ((i == j + 3) ? 1.0f : 0.0f));
            *(u16x4*)(Bp + (size_t)i * NN + j) = u;
        }
    }
    __shared__ float red[4][256];
    *(float4*)&red[ir][jq * 4] = s;
    __syncthreads();
    float v = red[0][t] + red[1][t] + red[2][t] + red[3][t];
    atomicAdd(colsum + b * NN + jt * 256 + t, v);
}

// K2: blocks 0..255: XdTF = frag-linear bf16 of Xd^T (Xd[j][n]=rsqrt(1+cs[j])*X[j][n]).
//     blocks 256..271: WdT[fo][di] = bf16(W[di][fo])  (folded k_wt).
// XdTF layout: [b][c16(8)][ks(64)][lane(64)][8]; frag (c16,ks): lane (q,m16)
// holds Xd[ks*32+q*8 ..+8][c16*16+m16].
__global__ __launch_bounds__(256) void k_xdt(const float* __restrict__ X,
                                             const float* __restrict__ colsum,
                                             unsigned short* __restrict__ XdTF,
                                             const float* __restrict__ W,
                                             unsigned short* __restrict__ WdT) {
    int t = threadIdx.x;
    if (blockIdx.x >= 256) {          // W transpose tail
        int blk = blockIdx.x - 256;
        int di  = blk * 8 + (t >> 5);
        int fo4 = (t & 31) * 4;
        float4 v = *(const float4*)(W + di * NF + fo4);
        WdT[(fo4 + 0) * DF + di] = f2bf(v.x);
        WdT[(fo4 + 1) * DF + di] = f2bf(v.y);
        WdT[(fo4 + 2) * DF + di] = f2bf(v.z);
        WdT[(fo4 + 3) * DF + di] = f2bf(v.w);
        return;
    }
    __shared__ unsigned short T[128 * 72];   // [f][j_local 64->72 pad]
    int jt = blockIdx.x & 31;
    int b  = blockIdx.x >> 5;
    int j0 = jt * 64;
    int r = t >> 5;
    int c = t & 31;
#pragma unroll
    for (int p = 0; p < 8; p++) {
        int j = r + p * 8;
        float dv = rsqrtf(1.0f + colsum[b * NN + j0 + j]);
        float4 v = *(const float4*)(X + ((size_t)(b * NN + j0 + j)) * DF + c * 4);
        T[(c * 4 + 0) * 72 + j] = f2bf(v.x * dv);
        T[(c * 4 + 1) * 72 + j] = f2bf(v.y * dv);
        T[(c * 4 + 2) * 72 + j] = f2bf(v.z * dv);
        T[(c * 4 + 3) * 72 + j] = f2bf(v.w * dv);
    }
    __syncthreads();
    int ks0 = j0 >> 5;                        // 2 ks per block
#pragma unroll
    for (int rep = 0; rep < 4; rep++) {
        int ch   = rep * 256 + t;             // 1024 chunks: 2ks x 8c16 x 64lanes
        int lane = ch & 63;
        int c16  = (ch >> 6) & 7;
        int ksl  = ch >> 9;                   // 0..1
        int q = lane >> 4, m16 = lane & 15;
        u16x8 u = *(const u16x8*)&T[(c16 * 16 + m16) * 72 + ksl * 32 + q * 8];
        *(u16x8*)(XdTF + (((size_t)(b * 8 + c16) * 64 + ks0 + ksl) * 64 + lane) * 8) = u;
    }
}

// K3: pure-load MFMA GEMM, now 16 waves/block for 32 waves/CU (2x TLP).
// Wave (wr 0..1, wc 0..7) owns 16 rows x 16 cols; A-frag u16x8 from row-major
// Ab16, B-frag from frag-linear XdTF, both feed MFMA directly (zero VALU).
// Zero LDS/stores/barriers in K-loop. Epilogue: x d_i -> Ps -> H = relu(P@W).
// Grid 512 = 8b x 64mt (BM=32), 1024 thr. b = bid&7 pins batch b to XCD b.
__global__ __launch_bounds__(1024, 8) void k_gemm(const unsigned short* __restrict__ Ab16,
                                                  const unsigned short* __restrict__ XdTF,
                                                  const float* __restrict__ colsum,
                                                  const unsigned short* __restrict__ WdT,
                                                  float* __restrict__ H) {
    __shared__ unsigned short Ps[32 * 136];
    int bid = blockIdx.x;
    int b  = bid & 7;
    int mt = bid >> 3;                        // 0..63
    int t = threadIdx.x;
    int w = t >> 6, l = t & 63, m16 = l & 15, q = l >> 4;
    int wr = w >> 3;                          // 0..1
    int wc = w & 7;                           // 0..7
    const unsigned short* Xb = XdTF + (size_t)b * 8 * 64 * 512;
    int row = (mt * 2 + wr) * 16 + m16;
    const unsigned short* ap = Ab16 + (size_t)b * NN * NN + (size_t)row * NN + q * 8;
    const unsigned short* x0 = Xb + ((size_t)wc * 64) * 512 + l * 8;

    f32x4 acc0 = (f32x4){0.f, 0.f, 0.f, 0.f};
#pragma unroll 4
    for (int ks = 0; ks < 64; ks++) {
        bf16x8 af = __builtin_bit_cast(bf16x8, *(const u16x8*)(ap + ks * 32));
        bf16x8 b0 = __builtin_bit_cast(bf16x8, *(const u16x8*)(x0 + ks * 512));
        acc0 = __builtin_amdgcn_mfma_f32_16x16x32_bf16(af, b0, acc0, 0, 0, 0);
    }

    // epilogue 1: x d_i, pack P tile (bf16) to LDS
    int m0 = mt * 32;
#pragma unroll
    for (int r = 0; r < 4; r++) {
        float dv = rsqrtf(1.0f + colsum[b * NN + m0 + wr * 16 + q * 4 + r]);
        Ps[(wr * 16 + q * 4 + r) * 136 + wc * 16 + m16] = f2bf(acc0[r] * dv);
    }
    __syncthreads();

    // epilogue 2: H = relu(P @ W); wave (wr,wc) computes rows wr*16.., cols wc*16..
    f32x4 h0 = (f32x4){0.f, 0.f, 0.f, 0.f};
#pragma unroll
    for (int ks = 0; ks < 4; ks++) {
        bf16x8 pa = __builtin_bit_cast(bf16x8,
            *(const u16x8*)&Ps[(wr * 16 + m16) * 136 + ks * 32 + q * 8]);
        bf16x8 w0 = __builtin_bit_cast(bf16x8,
            *(const u16x8*)(WdT + (size_t)(wc * 16 + m16) * DF + ks * 32 + q * 8));
        h0 = __builtin_amdgcn_mfma_f32_16x16x32_bf16(pa, w0, h0, 0, 0, 0);
    }
#pragma unroll
    for (int r = 0; r < 4; r++) {
        int grow = m0 + wr * 16 + q * 4 + r;
        float v0 = h0[r] > 0.f ? h0[r] : 0.f;
        H[((size_t)(b * NN + grow)) * NF + wc * 16 + m16] = v0;
    }
}

extern "C" void kernel_launch(void* const* d_in, const int* in_sizes, int n_in,
                              void* d_out, int out_size, void* d_ws, size_t ws_size,
                              hipStream_t stream) {
    const float* A = (const float*)d_in[0];
    const float* X = (const float*)d_in[1];
    const float* W = (const float*)d_in[2];
    float* out  = (float*)d_out;
    float* outA = out;
    float* H    = out + (size_t)NB * NN * NN;   // tuple: (A, H) flat

    char* ws = (char*)d_ws;
    float* colsum        = (float*)ws;                          // 64 KB
    unsigned short* XdTF = (unsigned short*)(ws + (1 << 16));   // 4 MB
    unsigned short* WdT  = (unsigned short*)(ws + (1 << 16) + (4 << 20));              // 32 KB
    unsigned short* Ab16 = (unsigned short*)(ws + (1 << 16) + (4 << 20) + (1 << 15));  // 64 MB

    hipMemsetAsync(colsum, 0, 65536, stream);
    k_stream<<<2048, 256, 0, stream>>>(A, outA, Ab16, colsum);
    k_xdt<<<272, 256, 0, stream>>>(X, colsum, XdTF, W, WdT);
    k_gemm<<<512, 1024, 0, stream>>>(Ab16, XdTF, colsum, WdT, H);
}